// Round 1
// baseline (8380.746 us; speedup 1.0000x reference)
//
#include <hip/hip_runtime.h>
#include <hip/hip_bf16.h>

#define Bc 256
#define Tc 256
#define NOBS 512
#define NACT 8
#define NST 1024
#define Gc 64
#define Xc 32
#define Pc 128
#define Hc 128

typedef unsigned short u16;
typedef unsigned int u32;
typedef __attribute__((ext_vector_type(4))) float f32x4;
typedef __attribute__((ext_vector_type(8))) short bf16x8;

__device__ __forceinline__ u16 f2bf(float f) {
    __hip_bfloat16 h = __float2bfloat16(f);
    return __builtin_bit_cast(u16, h);
}
__device__ __forceinline__ float bf2f(u16 v) {
    u32 x = ((u32)v) << 16;
    return __builtin_bit_cast(float, x);
}
__device__ __forceinline__ u32 pack2(float a, float b) {
    return (u32)f2bf(a) | (((u32)f2bf(b)) << 16);
}
__device__ __forceinline__ float dot4(f32x4 a, f32x4 b) {
    return a.x * b.x + a.y * b.y + a.z * b.z + a.w * b.w;
}

// DPP cross-lane add: x + dpp_perm(x). VALU-speed (no DS pipe).
// 0xB1 = quad_perm [1,0,3,2] (xor1), 0x4E = quad_perm [2,3,0,1] (xor2),
// 0x141 = row_half_mirror (xor4-equivalent on quad-uniform data),
// 0x140 = row_mirror (xor8-equivalent on 8-uniform data).
template <int CTRL>
__device__ __forceinline__ float dpp_add(float x) {
    int xi = __builtin_bit_cast(int, x);
    int yi = __builtin_amdgcn_update_dpp(0, xi, CTRL, 0xF, 0xF, true);
    return x + __builtin_bit_cast(float, yi);
}

// Block-wide sum of two floats over 512 threads (8 waves).
// PRECONDITION: values duplicated x4 across lanes 4k..4k+3.
// Result: exact sum over the 128 distinct rows (no duplication factor).
__device__ __forceinline__ void blockReduce2(float& a, float& b, volatile float* red, int tid) {
    a = dpp_add<0x141>(a); b = dpp_add<0x141>(b);   // + other quad (rows)
    a = dpp_add<0x140>(a); b = dpp_add<0x140>(b);   // + other 8-group
    a += __shfl_xor(a, 16, 64); b += __shfl_xor(b, 16, 64);
    a += __shfl_xor(a, 32, 64); b += __shfl_xor(b, 32, 64);
    __syncthreads();  // WAR on red from previous use
    if ((tid & 63) == 0) { int w = tid >> 6; red[w] = a; red[8 + w] = b; }
    __syncthreads();
    a = ((red[0] + red[1]) + (red[2] + red[3])) + ((red[4] + red[5]) + (red[6] + red[7]));
    b = ((red[8] + red[9]) + (red[10] + red[11])) + ((red[12] + red[13]) + (red[14] + red[15]));
}

// ---------------------------------------------------------------------------
// Kernel 0: precompute tables.
//   hx_tab[o][r] = enc_b1[r] + obs_emb[o] . enc_w1[r][64:96]   (512x128)
//   gi_tab[a][row] = b_ih[row] + act_emb[a] . w_ih[row]        (8x192)
// Only 512 obs values / 8 actions exist -> the per-step gi matvec and the
// x-half of enc1 become table lookups.
// ---------------------------------------------------------------------------
__global__ __launch_bounds__(256) void precompute_tabs(
    const float* __restrict__ obs_emb, const float* __restrict__ act_emb,
    const float* __restrict__ w_ih, const float* __restrict__ b_ih,
    const float* __restrict__ enc_w1, const float* __restrict__ enc_b1,
    float* __restrict__ hx_tab, float* __restrict__ gi_tab)
{
    int idx = blockIdx.x * 256 + threadIdx.x;
    if (idx < NOBS * Hc) {
        int o = idx >> 7, rr = idx & 127;
        const f32x4* oe = (const f32x4*)(obs_emb + o * Xc);
        const f32x4* w = (const f32x4*)(enc_w1 + rr * (Gc + Xc) + Gc);
        float s = enc_b1[rr];
#pragma unroll
        for (int j = 0; j < 8; ++j) s += dot4(oe[j], w[j]);
        hx_tab[idx] = s;
    } else if (idx < NOBS * Hc + NACT * 3 * Gc) {
        int k = idx - NOBS * Hc;
        int a = k / 192, row = k - a * 192;
        const f32x4* ae = (const f32x4*)(act_emb + a * Gc);
        const f32x4* w = (const f32x4*)(w_ih + row * Gc);
        float s = b_ih[row];
#pragma unroll
        for (int j = 0; j < 16; ++j) s += dot4(ae[j], w[j]);
        gi_tab[k] = s;
    }
}

// ---------------------------------------------------------------------------
// Kernel 1: fused sequential scan. One block of 512 threads per batch element.
// Thread (r=tid>>2, q=tid&3) owns M[r][q*32 .. q*32+31] in registers.
// Retrieval collapse extended: (kI+M) is linear, so
//   q3 = l2n((kI+M)^3 l2n(pval)) = l2n((kI+M)^3 pval)
// -> no normalization needed before retrieval; pn-norm and q-norm share ONE
// combined block reduce. M update uses unnormalized qA + scalar 0.4*pn_r*inv.
// ---------------------------------------------------------------------------
__global__ __launch_bounds__(512, 2) void scan_kernel(
    const int* __restrict__ obs, const int* __restrict__ actions,
    const float* __restrict__ g_init,
    const float* __restrict__ w_hh, const float* __restrict__ b_hh,
    const float* __restrict__ enc_w1,
    const float* __restrict__ ln_g, const float* __restrict__ ln_b,
    const float* __restrict__ enc_w2, const float* __restrict__ enc_b2,
    const float* __restrict__ hx_tab, const float* __restrict__ gi_tab,
    float* __restrict__ outP, float* __restrict__ outPM,
    float* __restrict__ accs)
{
    int b = blockIdx.x;
    int tid = threadIdx.x;
    int r = tid >> 2, q = tid & 3;

    __shared__ int obs_lds[Tc];
    __shared__ int act_lds[Tc];
    __shared__ __align__(16) float gitab[NACT * 3 * Gc];  // 6 KB
    __shared__ __align__(16) float gx[Gc];
    __shared__ __align__(16) float ghl[3 * Gc];
    __shared__ __align__(16) float bhhs[3 * Gc];
    __shared__ __align__(16) float hv[Hc];
    __shared__ __align__(16) float qA[Pc];
    __shared__ __align__(16) float qB[Pc];
    __shared__ __align__(16) float qC[Pc];
    __shared__ __align__(16) float lngs[Hc];
    __shared__ __align__(16) float lnbs[Hc];
    __shared__ __align__(16) float b2s[Pc];
    __shared__ volatile float red[16];

    if (tid < 256) obs_lds[tid] = obs[b * Tc + tid];
    else           act_lds[tid - 256] = actions[b * Tc + (tid - 256)];
    for (int i = tid; i < NACT * 3 * Gc; i += 512) gitab[i] = gi_tab[i];
    if (tid < 3 * Gc) bhhs[tid] = b_hh[tid];
    if (tid < Hc) { lngs[tid] = ln_g[tid]; lnbs[tid] = ln_b[tid]; b2s[tid] = enc_b2[tid]; }
    if (tid < Gc) gx[tid] = g_init[tid];

    // per-thread weight registers
    float whh[32];
    if (tid < 384) {
        int row = tid >> 1, hh = tid & 1;
        const f32x4* p = (const f32x4*)(w_hh + row * Gc + hh * 32);
#pragma unroll
        for (int i = 0; i < 8; ++i) ((f32x4*)whh)[i] = p[i];
    }
    float w1r[16];
    {
        const f32x4* p = (const f32x4*)(enc_w1 + r * (Gc + Xc) + q * 16);
#pragma unroll
        for (int i = 0; i < 4; ++i) ((f32x4*)w1r)[i] = p[i];
    }
    float w2r[32];
    {
        const f32x4* p = (const f32x4*)(enc_w2 + r * Hc + q * 32);
#pragma unroll
        for (int i = 0; i < 8; ++i) ((f32x4*)w2r)[i] = p[i];
    }

    float Mreg[32];
#pragma unroll
    for (int i = 0; i < 32; ++i) Mreg[i] = 0.f;

    float pnprev = 0.f, lmacc = 0.f;
    __syncthreads();

    float hx = hx_tab[obs_lds[0] * Hc + r];  // includes b1 + x-part

    for (int t = 0; t < Tc; ++t) {
        // ---- P1: prefetch next hx row; GRU gh pre-activations (384 thr) ----
        int tn = (t + 1 < Tc) ? t + 1 : t;
        float hxn = hx_tab[obs_lds[tn] * Hc + r];
        int ai = (t > 0) ? act_lds[t - 1] : 0;
        if (t > 0 && tid < 384) {
            int row = tid >> 1, hh = tid & 1;
            const f32x4* g4 = (const f32x4*)gx;
            float s2 = 0.f;
#pragma unroll
            for (int m = 0; m < 8; ++m) s2 += dot4(g4[hh * 8 + m], ((const f32x4*)whh)[m]);
            s2 = dpp_add<0xB1>(s2);  // combine the two halves
            if (hh == 0) ghl[row] = s2 + bhhs[row];
        }
        __syncthreads();

        // ---- P2: gate math, 64 threads ----
        if (t > 0 && tid < 64) {
            const float* git = gitab + ai * 192;
            float ir = git[tid], iz = git[64 + tid], inn = git[128 + tid];
            float hr = ghl[tid], hz = ghl[64 + tid], hn2 = ghl[128 + tid];
            float rr = 1.f / (1.f + __expf(-(ir + hr)));
            float zz = 1.f / (1.f + __expf(-(iz + hz)));
            float nn = tanhf(inn + rr * hn2);
            gx[tid] = (1.f - zz) * nn + zz * gx[tid];
        }
        __syncthreads();

        // ---- P3: enc1 (g-part only; x-part + b1 from hx table) + LayerNorm ----
        float hval;
        {
            const f32x4* g4 = (const f32x4*)gx;
            float s = 0.f;
#pragma unroll
            for (int m = 0; m < 4; ++m) s += dot4(g4[q * 4 + m], ((const f32x4*)w1r)[m]);
            s = dpp_add<0xB1>(s);
            s = dpp_add<0x4E>(s);
            hval = s + hx;
        }
        float s1 = hval, s2 = hval * hval;
        blockReduce2(s1, s2, red, tid);
        float mu = s1 * (1.f / 128.f);
        float var = s2 * (1.f / 128.f) - mu * mu;
        float hn = fmaxf((hval - mu) * rsqrtf(var + 1e-5f) * lngs[r] + lnbs[r], 0.f);
        if (q == 0) hv[r] = hn;
        __syncthreads();

        // ---- P5: enc2 (rotated LDS reads: distinct bank groups per quarter) ----
        float pval;
        {
            const f32x4* h4 = (const f32x4*)hv;
            float s = 0.f;
#pragma unroll
            for (int m = 0; m < 8; ++m) {
                int mr = (m + 2 * q) & 7;
                s += dot4(h4[q * 8 + mr], ((const f32x4*)w2r)[mr]);
            }
            s = dpp_add<0xB1>(s);
            s = dpp_add<0x4E>(s);
            pval = fmaxf(s + b2s[r], 0.f) + 1e-6f;
        }
        if (q == 0) qA[r] = pval;
        __syncthreads();

        // ---- P6: retrieval v = (kI+M)^3 pval (unnormalized) ----
        float v;
        {
            const f32x4* q4 = (const f32x4*)qA;
            float ss = 0.f;
#pragma unroll
            for (int m = 0; m < 8; ++m) {
                int mr = (m + 2 * q) & 7;
                ss += dot4(q4[q * 8 + mr], ((const f32x4*)Mreg)[mr]);
            }
            ss = dpp_add<0xB1>(ss);
            ss = dpp_add<0x4E>(ss);
            v = 0.8f * pval + ss;
            if (q == 0) qB[r] = v;
        }
        __syncthreads();
        {
            const f32x4* q4 = (const f32x4*)qB;
            float ss = 0.f;
#pragma unroll
            for (int m = 0; m < 8; ++m) {
                int mr = (m + 2 * q) & 7;
                ss += dot4(q4[q * 8 + mr], ((const f32x4*)Mreg)[mr]);
            }
            ss = dpp_add<0xB1>(ss);
            ss = dpp_add<0x4E>(ss);
            v = 0.8f * v + ss;
            if (q == 0) qC[r] = v;
        }
        __syncthreads();
        {
            const f32x4* q4 = (const f32x4*)qC;
            float ss = 0.f;
#pragma unroll
            for (int m = 0; m < 8; ++m) {
                int mr = (m + 2 * q) & 7;
                ss += dot4(q4[q * 8 + mr], ((const f32x4*)Mreg)[mr]);
            }
            ss = dpp_add<0xB1>(ss);
            ss = dpp_add<0x4E>(ss);
            v = 0.8f * v + ss;
        }

        // ---- P7: ONE combined reduce for ||pval|| and ||v|| ----
        float t1 = pval * pval, t2 = v * v;
        blockReduce2(t1, t2, red, tid);
        float inv_np = 1.f / fmaxf(sqrtf(t1), 1e-12f);
        float inv3 = 1.f / fmaxf(sqrtf(t2), 1e-12f);
        float pn = pval * inv_np;
        float pm = v * inv3;
        size_t rowoff = ((size_t)(b * Tc + t)) << 7;
        if (q == 0) {
            outP[rowoff + r] = pn;
            outPM[rowoff + r] = pm;
            if (t > 0) { float d = pm - pnprev; lmacc += d * d; }
        }
        pnprev = pn;

        // ---- P8: M = 0.995*M + 0.4*pn pn^T  (= 0.4*inv^2 * pval pval^T) ----
        {
            float cc = 0.4f * pn * inv_np;
            const f32x4* p4 = (const f32x4*)qA;
#pragma unroll
            for (int m = 0; m < 8; ++m) {
                int mr = (m + 2 * q) & 7;
                f32x4 pv = p4[q * 8 + mr];
                f32x4 mm = ((const f32x4*)Mreg)[mr];
                mm = 0.995f * mm + cc * pv;
                ((f32x4*)Mreg)[mr] = mm;
            }
        }
        hx = hxn;
    }

    // final mem-loss reduce: lmacc nonzero only on q==0 lanes (exact, no dup)
    float z = lmacc;
    z = dpp_add<0xB1>(z);
    z = dpp_add<0x4E>(z);
    z = dpp_add<0x141>(z);
    z = dpp_add<0x140>(z);
    z += __shfl_xor(z, 16, 64);
    z += __shfl_xor(z, 32, 64);
    __syncthreads();
    if ((tid & 63) == 0) red[tid >> 6] = z;
    __syncthreads();
    if (tid == 0) {
        float s = ((red[0] + red[1]) + (red[2] + red[3])) + ((red[4] + red[5]) + (red[6] + red[7]));
        atomicAdd(&accs[2], s);
    }
}

// ---------------------------------------------------------------------------
// Kernel 2: decoder GEMM, f32 in/out, bf16 MFMA inside.
// ---------------------------------------------------------------------------
__global__ __launch_bounds__(256, 2) void dec_gemm(
    const float* __restrict__ pn_, const float* __restrict__ pm_,
    const float* __restrict__ wo, const float* __restrict__ bo,
    const float* __restrict__ wsd, const float* __restrict__ bsd,
    float* __restrict__ outO, float* __restrict__ outS)
{
    __shared__ u16 As[128 * 136];
    __shared__ u16 Bs[128 * 136];
    __shared__ float rnorm[128];
    int cb = blockIdx.x;
    int rowbase = blockIdx.y * 128;
    const float* W; const float* bias; float* out; int Nw; int colbase;
    if (cb < 4) { W = wo; bias = bo; out = outO; Nw = 512; colbase = cb * 128; }
    else        { W = wsd; bias = bsd; out = outS; Nw = 1024; colbase = (cb - 4) * 128; }
    int tid = threadIdx.x;
    for (int i = tid; i < 2048; i += 256) {
        int row = i >> 4, kb = i & 15;
        size_t go = ((size_t)(rowbase + row)) * 128 + kb * 8;
        f32x4 a0 = *(const f32x4*)(pn_ + go);
        f32x4 a1 = *(const f32x4*)(pn_ + go + 4);
        f32x4 m0v = *(const f32x4*)(pm_ + go);
        f32x4 m1v = *(const f32x4*)(pm_ + go + 4);
        f32x4 v0 = a0 + m0v, v1 = a1 + m1v;
        uint4 vv;
        vv.x = pack2(v0.x, v0.y); vv.y = pack2(v0.z, v0.w);
        vv.z = pack2(v1.x, v1.y); vv.w = pack2(v1.z, v1.w);
        *(uint4*)(As + row * 136 + kb * 8) = vv;
        size_t gw = ((size_t)(colbase + row)) * 128 + kb * 8;
        f32x4 w0 = *(const f32x4*)(W + gw);
        f32x4 w1 = *(const f32x4*)(W + gw + 4);
        uint4 wv;
        wv.x = pack2(w0.x, w0.y); wv.y = pack2(w0.z, w0.w);
        wv.z = pack2(w1.x, w1.y); wv.w = pack2(w1.z, w1.w);
        *(uint4*)(Bs + row * 136 + kb * 8) = wv;
    }
    __syncthreads();
    {
        int rr = tid >> 1, hh = tid & 1;
        const u16* rowp = As + rr * 136 + hh * 64;
        float ss = 0.f;
#pragma unroll
        for (int i = 0; i < 64; ++i) { float x = bf2f(rowp[i]); ss += x * x; }
        ss += __shfl_xor(ss, 1, 64);
        if (hh == 0) rnorm[rr] = 1.f / fmaxf(sqrtf(ss), 1e-12f);
    }
    __syncthreads();
    int wv_ = tid >> 6, lane = tid & 63;
    int m0 = (wv_ & 1) * 64, n0 = (wv_ >> 1) * 64;
    int lr = lane & 15, lq = lane >> 4;
    const f32x4 vzero = {0.f, 0.f, 0.f, 0.f};
    f32x4 acc[4][4];
#pragma unroll
    for (int a = 0; a < 4; ++a)
#pragma unroll
        for (int c = 0; c < 4; ++c) acc[a][c] = vzero;
#pragma unroll
    for (int ks = 0; ks < 4; ++ks) {
        bf16x8 af[4], bfr[4];
#pragma unroll
        for (int i = 0; i < 4; ++i) {
            af[i]  = *(const bf16x8*)(As + (m0 + i * 16 + lr) * 136 + ks * 32 + lq * 8);
            bfr[i] = *(const bf16x8*)(Bs + (n0 + i * 16 + lr) * 136 + ks * 32 + lq * 8);
        }
#pragma unroll
        for (int mi = 0; mi < 4; ++mi)
#pragma unroll
            for (int ni = 0; ni < 4; ++ni)
                acc[mi][ni] = __builtin_amdgcn_mfma_f32_16x16x32_bf16(af[mi], bfr[ni], acc[mi][ni], 0, 0, 0);
    }
#pragma unroll
    for (int ni = 0; ni < 4; ++ni) {
        int col = colbase + n0 + ni * 16 + lr;
        float bb = bias[col];
#pragma unroll
        for (int mi = 0; mi < 4; ++mi) {
            int rloc = m0 + mi * 16 + lq * 4;
            int row = rowbase + rloc;
#pragma unroll
            for (int k2 = 0; k2 < 4; ++k2) {
                out[((size_t)(row + k2)) * Nw + col] = acc[mi][ni][k2] * rnorm[rloc + k2] + bb;
            }
        }
    }
}

// ---------------------------------------------------------------------------
// Kernel 3: per-row logsumexp CE losses, f32 logits. One wave per row.
// ---------------------------------------------------------------------------
__global__ __launch_bounds__(256) void loss_rows(
    const float* __restrict__ lo_, const float* __restrict__ ls_,
    const int* __restrict__ obs, const int* __restrict__ states,
    float* __restrict__ accs)
{
    __shared__ float part[8];
    int wv = threadIdx.x >> 6, lane = threadIdx.x & 63;
    float accO = 0.f, accS = 0.f;
    int rowbase = blockIdx.x * 128 + wv * 32;
    for (int i = 0; i < 32; ++i) {
        int row = rowbase + i;
        {
            const float* ro = lo_ + ((size_t)row << 9);
            f32x4 u0 = *(const f32x4*)(ro + lane * 8);
            f32x4 u1 = *(const f32x4*)(ro + lane * 8 + 4);
            float m = fmaxf(fmaxf(fmaxf(u0.x, u0.y), fmaxf(u0.z, u0.w)),
                            fmaxf(fmaxf(u1.x, u1.y), fmaxf(u1.z, u1.w)));
#pragma unroll
            for (int k = 1; k < 64; k <<= 1) m = fmaxf(m, __shfl_xor(m, k, 64));
            float se = __expf(u0.x - m) + __expf(u0.y - m) + __expf(u0.z - m) + __expf(u0.w - m) +
                       __expf(u1.x - m) + __expf(u1.y - m) + __expf(u1.z - m) + __expf(u1.w - m);
#pragma unroll
            for (int k = 1; k < 64; k <<= 1) se += __shfl_xor(se, k, 64);
            float lse = m + __logf(se);
            float xt = ro[obs[row]];
            if (lane == 0) accO += lse - xt;
        }
        {
            const float* rs = ls_ + ((size_t)row << 10);
            f32x4 u0 = *(const f32x4*)(rs + lane * 16);
            f32x4 u1 = *(const f32x4*)(rs + lane * 16 + 4);
            f32x4 u2 = *(const f32x4*)(rs + lane * 16 + 8);
            f32x4 u3 = *(const f32x4*)(rs + lane * 16 + 12);
            float m = fmaxf(fmaxf(fmaxf(u0.x, u0.y), fmaxf(u0.z, u0.w)),
                            fmaxf(fmaxf(u1.x, u1.y), fmaxf(u1.z, u1.w)));
            m = fmaxf(m, fmaxf(fmaxf(fmaxf(u2.x, u2.y), fmaxf(u2.z, u2.w)),
                               fmaxf(fmaxf(u3.x, u3.y), fmaxf(u3.z, u3.w))));
#pragma unroll
            for (int k = 1; k < 64; k <<= 1) m = fmaxf(m, __shfl_xor(m, k, 64));
            float se = __expf(u0.x - m) + __expf(u0.y - m) + __expf(u0.z - m) + __expf(u0.w - m) +
                       __expf(u1.x - m) + __expf(u1.y - m) + __expf(u1.z - m) + __expf(u1.w - m) +
                       __expf(u2.x - m) + __expf(u2.y - m) + __expf(u2.z - m) + __expf(u2.w - m) +
                       __expf(u3.x - m) + __expf(u3.y - m) + __expf(u3.z - m) + __expf(u3.w - m);
#pragma unroll
            for (int k = 1; k < 64; k <<= 1) se += __shfl_xor(se, k, 64);
            float lse = m + __logf(se);
            float xt = rs[states[row]];
            if (lane == 0) accS += lse - xt;
        }
    }
    if (lane == 0) { part[wv] = accO; part[4 + wv] = accS; }
    __syncthreads();
    if (threadIdx.x == 0) {
        atomicAdd(&accs[0], part[0] + part[1] + part[2] + part[3]);
        atomicAdd(&accs[1], part[4] + part[5] + part[6] + part[7]);
    }
}

__global__ void finalize_kernel(const float* __restrict__ accs, float* __restrict__ out_loss)
{
    float lo = accs[0] * (1.f / 65536.f);
    float ls = accs[1] * (1.f / 65536.f);
    float lm = accs[2] * (1.f / (256.f * 255.f * 128.f));
    out_loss[0] = lo + 0.1f * lm + ls;
}

extern "C" void kernel_launch(void* const* d_in, const int* in_sizes, int n_in,
                              void* d_out, int out_size, void* d_ws, size_t ws_size,
                              hipStream_t stream)
{
    const int* obs        = (const int*)d_in[0];
    const int* actions    = (const int*)d_in[1];
    const int* states     = (const int*)d_in[2];
    const float* obs_emb  = (const float*)d_in[3];
    const float* act_emb  = (const float*)d_in[4];
    const float* g_init   = (const float*)d_in[5];
    const float* w_ih     = (const float*)d_in[6];
    const float* w_hh     = (const float*)d_in[7];
    const float* b_ih     = (const float*)d_in[8];
    const float* b_hh     = (const float*)d_in[9];
    const float* enc_w1   = (const float*)d_in[10];
    const float* enc_b1   = (const float*)d_in[11];
    const float* ln_g     = (const float*)d_in[12];
    const float* ln_b     = (const float*)d_in[13];
    const float* enc_w2   = (const float*)d_in[14];
    const float* enc_b2   = (const float*)d_in[15];
    const float* dec_obs_w = (const float*)d_in[16];
    const float* dec_obs_b = (const float*)d_in[17];
    const float* dec_st_w  = (const float*)d_in[18];
    const float* dec_st_b  = (const float*)d_in[19];

    float* out = (float*)d_out;
    float* outO    = out;                            // (B,T,512)
    float* outS    = out + (size_t)33554432;         // (B,T,1024)
    float* outP    = out + (size_t)100663296;        // (B,T,128) p_norm
    float* outPM   = out + (size_t)109051904;        // (B,T,128) p_mem
    float* outLoss = out + (size_t)117440512;        // scalar

    // scratch tables live at the start of the outS region: they are consumed
    // by scan_kernel and later fully overwritten by dec_gemm. Zero ws risk.
    float* hx_tab = outS;                 // 512*128 floats
    float* gi_tab = outS + 65536;         // 8*192 floats

    float* accs = (float*)d_ws;  // [0]=obs CE sum [1]=state CE sum [2]=mem MSE sum

    hipMemsetAsync(d_ws, 0, 64, stream);
    precompute_tabs<<<dim3(262), dim3(256), 0, stream>>>(
        obs_emb, act_emb, w_ih, b_ih, enc_w1, enc_b1, hx_tab, gi_tab);
    scan_kernel<<<dim3(256), dim3(512), 0, stream>>>(
        obs, actions, g_init, w_hh, b_hh,
        enc_w1, ln_g, ln_b, enc_w2, enc_b2, hx_tab, gi_tab, outP, outPM, accs);
    dec_gemm<<<dim3(12, 512), dim3(256), 0, stream>>>(
        outP, outPM, dec_obs_w, dec_obs_b, dec_st_w, dec_st_b, outO, outS);
    loss_rows<<<dim3(512), dim3(256), 0, stream>>>(outO, outS, obs, states, accs);
    finalize_kernel<<<dim3(1), dim3(1), 0, stream>>>(accs, outLoss);
}

// Round 4
// 1639.720 us; speedup vs baseline: 5.1111x; 5.1111x over previous
//
#include <hip/hip_runtime.h>
#include <hip/hip_bf16.h>

#define Bc 256
#define Tc 256
#define NOBS 512
#define NACT 8
#define NST 1024
#define Gc 64
#define Xc 32
#define Pc 128
#define Hc 128

typedef unsigned short u16;
typedef unsigned int u32;
typedef __attribute__((ext_vector_type(4))) float f32x4;
typedef __attribute__((ext_vector_type(8))) short bf16x8;

__device__ __forceinline__ u16 f2bf(float f) {
    __hip_bfloat16 h = __float2bfloat16(f);
    return __builtin_bit_cast(u16, h);
}
__device__ __forceinline__ float bf2f(u16 v) {
    u32 x = ((u32)v) << 16;
    return __builtin_bit_cast(float, x);
}
__device__ __forceinline__ u32 pack2(float a, float b) {
    return (u32)f2bf(a) | (((u32)f2bf(b)) << 16);
}
__device__ __forceinline__ float dot4(f32x4 a, f32x4 b) {
    return a.x * b.x + a.y * b.y + a.z * b.z + a.w * b.w;
}

// DPP cross-lane add: x + dpp_perm(x). VALU-speed (no DS pipe).
// 0xB1 = quad_perm [1,0,3,2] (xor1), 0x4E = quad_perm [2,3,0,1] (xor2),
// 0x141 = row_half_mirror, 0x140 = row_mirror.
template <int CTRL>
__device__ __forceinline__ float dpp_add(float x) {
    int xi = __builtin_bit_cast(int, x);
    int yi = __builtin_amdgcn_update_dpp(0, xi, CTRL, 0xF, 0xF, true);
    return x + __builtin_bit_cast(float, yi);
}

// Block-wide sum of two floats over 512 threads (8 waves).
// PRECONDITION: values duplicated x4 across lanes 4k..4k+3.
// Result: exact sum over the 128 distinct rows (duplication absorbed by
// skipping the xor1/xor2 butterfly levels).
__device__ __forceinline__ void blockReduce2(float& a, float& b, volatile float* red, int tid) {
    a = dpp_add<0x141>(a); b = dpp_add<0x141>(b);   // + other quad (rows)
    a = dpp_add<0x140>(a); b = dpp_add<0x140>(b);   // + other 8-group
    a += __shfl_xor(a, 16, 64); b += __shfl_xor(b, 16, 64);
    a += __shfl_xor(a, 32, 64); b += __shfl_xor(b, 32, 64);
    __syncthreads();  // WAR protection on red from previous use
    if ((tid & 63) == 0) { int w = tid >> 6; red[w] = a; red[8 + w] = b; }
    __syncthreads();
    a = ((red[0] + red[1]) + (red[2] + red[3])) + ((red[4] + red[5]) + (red[6] + red[7]));
    b = ((red[8] + red[9]) + (red[10] + red[11])) + ((red[12] + red[13]) + (red[14] + red[15]));
}

// ---------------------------------------------------------------------------
// Kernel 0: precompute tables.
//   hx_tab[o][r] = enc_b1[r] + obs_emb[o] . enc_w1[r][64:96]   (512x128)
//   gi_tab[a][row] = b_ih[row] + act_emb[a] . w_ih[row]        (8x192)
// ---------------------------------------------------------------------------
__global__ __launch_bounds__(256) void precompute_tabs(
    const float* __restrict__ obs_emb, const float* __restrict__ act_emb,
    const float* __restrict__ w_ih, const float* __restrict__ b_ih,
    const float* __restrict__ enc_w1, const float* __restrict__ enc_b1,
    float* __restrict__ hx_tab, float* __restrict__ gi_tab)
{
    int idx = blockIdx.x * 256 + threadIdx.x;
    if (idx < NOBS * Hc) {
        int o = idx >> 7, rr = idx & 127;
        const f32x4* oe = (const f32x4*)(obs_emb + o * Xc);
        const f32x4* w = (const f32x4*)(enc_w1 + rr * (Gc + Xc) + Gc);
        float s = enc_b1[rr];
#pragma unroll
        for (int j = 0; j < 8; ++j) s += dot4(oe[j], w[j]);
        hx_tab[idx] = s;
    } else if (idx < NOBS * Hc + NACT * 3 * Gc) {
        int k = idx - NOBS * Hc;
        int a = k / 192, row = k - a * 192;
        const f32x4* ae = (const f32x4*)(act_emb + a * Gc);
        const f32x4* w = (const f32x4*)(w_ih + row * Gc);
        float s = b_ih[row];
#pragma unroll
        for (int j = 0; j < 16; ++j) s += dot4(ae[j], w[j]);
        gi_tab[k] = s;
    }
}

// ---------------------------------------------------------------------------
// Kernel 1: fused sequential scan. One block of 512 threads per batch element.
// Thread (r=tid>>2, q=tid&3) owns M[r][q*32 .. q*32+31] in registers.
// RULE-#20 FIX: register arrays (Mreg, w2r) are stored in PRE-ROTATED
// physical order so every register index is compile-time static; only the
// LDS addresses carry the runtime (m+2q)&7 rotation.
// ---------------------------------------------------------------------------
__global__ __launch_bounds__(512, 2) void scan_kernel(
    const int* __restrict__ obs, const int* __restrict__ actions,
    const float* __restrict__ g_init,
    const float* __restrict__ w_hh, const float* __restrict__ b_hh,
    const float* __restrict__ enc_w1,
    const float* __restrict__ ln_g, const float* __restrict__ ln_b,
    const float* __restrict__ enc_w2, const float* __restrict__ enc_b2,
    const float* __restrict__ hx_tab, const float* __restrict__ gi_tab,
    float* __restrict__ outP, float* __restrict__ outPM,
    float* __restrict__ accs)
{
    int b = blockIdx.x;
    int tid = threadIdx.x;
    int r = tid >> 2, q = tid & 3;

    __shared__ int obs_lds[Tc];
    __shared__ int act_lds[Tc];
    __shared__ __align__(16) float gitab[NACT * 3 * Gc];  // 6 KB
    __shared__ __align__(16) float gx[Gc];
    __shared__ __align__(16) float ghl[3 * Gc];
    __shared__ __align__(16) float bhhs[3 * Gc];
    __shared__ __align__(16) float hv[Hc];
    __shared__ __align__(16) float qA[Pc];
    __shared__ __align__(16) float qB[Pc];
    __shared__ __align__(16) float qC[Pc];
    __shared__ __align__(16) float lngs[Hc];
    __shared__ __align__(16) float lnbs[Hc];
    __shared__ __align__(16) float b2s[Pc];
    __shared__ volatile float red[16];

    if (tid < 256) obs_lds[tid] = obs[b * Tc + tid];
    else           act_lds[tid - 256] = actions[b * Tc + (tid - 256)];
    for (int i = tid; i < NACT * 3 * Gc; i += 512) gitab[i] = gi_tab[i];
    if (tid < 3 * Gc) bhhs[tid] = b_hh[tid];
    if (tid < Hc) { lngs[tid] = ln_g[tid]; lnbs[tid] = ln_b[tid]; b2s[tid] = enc_b2[tid]; }
    if (tid < Gc) gx[tid] = g_init[tid];

    // per-thread weight registers (ALL statically indexed from here on)
    float whh[32];
    if (tid < 384) {
        int row = tid >> 1, hh = tid & 1;
        const f32x4* p = (const f32x4*)(w_hh + row * Gc + hh * 32);
#pragma unroll
        for (int i = 0; i < 8; ++i) ((f32x4*)whh)[i] = p[i];
    }
    float w1r[16];
    {
        const f32x4* p = (const f32x4*)(enc_w1 + r * (Gc + Xc) + q * 16);
#pragma unroll
        for (int i = 0; i < 4; ++i) ((f32x4*)w1r)[i] = p[i];
    }
    // w2r in PRE-ROTATED order: phys chunk m holds logical chunk (m+2q)&7
    float w2r[32];
    {
        const f32x4* p = (const f32x4*)(enc_w2 + r * Hc + q * 32);
#pragma unroll
        for (int i = 0; i < 8; ++i) ((f32x4*)w2r)[i] = p[(i + 2 * q) & 7];
    }

    // Mreg in the same rotated physical order (zeros at init, order-invariant)
    float Mreg[32];
#pragma unroll
    for (int i = 0; i < 32; ++i) Mreg[i] = 0.f;

    float pnprev = 0.f, lmacc = 0.f;
    __syncthreads();

    float hx = hx_tab[obs_lds[0] * Hc + r];  // includes b1 + x-part

    for (int t = 0; t < Tc; ++t) {
        // ---- P1: prefetch next hx row; GRU gh pre-activations (384 thr) ----
        int tn = (t + 1 < Tc) ? t + 1 : t;
        float hxn = hx_tab[obs_lds[tn] * Hc + r];
        int ai = (t > 0) ? act_lds[t - 1] : 0;
        if (t > 0 && tid < 384) {
            int row = tid >> 1, hh = tid & 1;
            const f32x4* g4 = (const f32x4*)gx;
            float s2 = 0.f;
#pragma unroll
            for (int m = 0; m < 8; ++m) s2 += dot4(g4[hh * 8 + m], ((const f32x4*)whh)[m]);
            s2 = dpp_add<0xB1>(s2);  // combine the two halves
            if (hh == 0) ghl[row] = s2 + bhhs[row];
        }
        __syncthreads();

        // ---- P2: gate math, 64 threads ----
        if (t > 0 && tid < 64) {
            const float* git = gitab + ai * 192;
            float ir = git[tid], iz = git[64 + tid], inn = git[128 + tid];
            float hr = ghl[tid], hz = ghl[64 + tid], hn2 = ghl[128 + tid];
            float rr = 1.f / (1.f + __expf(-(ir + hr)));
            float zz = 1.f / (1.f + __expf(-(iz + hz)));
            float nn = tanhf(inn + rr * hn2);
            gx[tid] = (1.f - zz) * nn + zz * gx[tid];
        }
        __syncthreads();

        // ---- P3: enc1 (g-part only; x-part + b1 from hx table) + LayerNorm ----
        float hval;
        {
            const f32x4* g4 = (const f32x4*)gx;
            float s = 0.f;
#pragma unroll
            for (int m = 0; m < 4; ++m) s += dot4(g4[q * 4 + m], ((const f32x4*)w1r)[m]);
            s = dpp_add<0xB1>(s);
            s = dpp_add<0x4E>(s);
            hval = s + hx;
        }
        float s1 = hval, s2 = hval * hval;
        blockReduce2(s1, s2, red, tid);
        float mu = s1 * (1.f / 128.f);
        float var = s2 * (1.f / 128.f) - mu * mu;
        float hn = fmaxf((hval - mu) * rsqrtf(var + 1e-5f) * lngs[r] + lnbs[r], 0.f);
        if (q == 0) hv[r] = hn;
        __syncthreads();

        // ---- P5: enc2. LDS address rotated; register index STATIC ----
        float pval;
        {
            const f32x4* h4 = (const f32x4*)hv;
            float s = 0.f;
#pragma unroll
            for (int m = 0; m < 8; ++m) {
                s += dot4(h4[q * 8 + ((m + 2 * q) & 7)], ((const f32x4*)w2r)[m]);
            }
            s = dpp_add<0xB1>(s);
            s = dpp_add<0x4E>(s);
            pval = fmaxf(s + b2s[r], 0.f) + 1e-6f;
        }
        if (q == 0) qA[r] = pval;
        __syncthreads();

        // ---- P6: retrieval v = (kI+M)^3 pval (unnormalized) ----
        float v;
        {
            const f32x4* q4 = (const f32x4*)qA;
            float ss = 0.f;
#pragma unroll
            for (int m = 0; m < 8; ++m)
                ss += dot4(q4[q * 8 + ((m + 2 * q) & 7)], ((const f32x4*)Mreg)[m]);
            ss = dpp_add<0xB1>(ss);
            ss = dpp_add<0x4E>(ss);
            v = 0.8f * pval + ss;
            if (q == 0) qB[r] = v;
        }
        __syncthreads();
        {
            const f32x4* q4 = (const f32x4*)qB;
            float ss = 0.f;
#pragma unroll
            for (int m = 0; m < 8; ++m)
                ss += dot4(q4[q * 8 + ((m + 2 * q) & 7)], ((const f32x4*)Mreg)[m]);
            ss = dpp_add<0xB1>(ss);
            ss = dpp_add<0x4E>(ss);
            v = 0.8f * v + ss;
            if (q == 0) qC[r] = v;
        }
        __syncthreads();
        {
            const f32x4* q4 = (const f32x4*)qC;
            float ss = 0.f;
#pragma unroll
            for (int m = 0; m < 8; ++m)
                ss += dot4(q4[q * 8 + ((m + 2 * q) & 7)], ((const f32x4*)Mreg)[m]);
            ss = dpp_add<0xB1>(ss);
            ss = dpp_add<0x4E>(ss);
            v = 0.8f * v + ss;
        }

        // ---- P7: ONE combined reduce for ||pval|| and ||v|| ----
        float t1 = pval * pval, t2 = v * v;
        blockReduce2(t1, t2, red, tid);
        float inv_np = 1.f / fmaxf(sqrtf(t1), 1e-12f);
        float inv3 = 1.f / fmaxf(sqrtf(t2), 1e-12f);
        float pn = pval * inv_np;
        float pm = v * inv3;
        size_t rowoff = ((size_t)(b * Tc + t)) << 7;
        if (q == 0) {
            outP[rowoff + r] = pn;
            outPM[rowoff + r] = pm;
            if (t > 0) { float d = pm - pnprev; lmacc += d * d; }
        }
        pnprev = pn;

        // ---- P8: M = 0.995*M + 0.4*pn pn^T (rotated phys order, static idx) ----
        {
            float cc = 0.4f * pn * inv_np;
            const f32x4* p4 = (const f32x4*)qA;
#pragma unroll
            for (int m = 0; m < 8; ++m) {
                f32x4 pv = p4[q * 8 + ((m + 2 * q) & 7)];
                f32x4 mm = ((const f32x4*)Mreg)[m];
                mm = 0.995f * mm + cc * pv;
                ((f32x4*)Mreg)[m] = mm;
            }
        }
        hx = hxn;
    }

    // final mem-loss reduce: lmacc nonzero only on q==0 lanes (exact, no dup)
    float z = lmacc;
    z = dpp_add<0xB1>(z);
    z = dpp_add<0x4E>(z);
    z = dpp_add<0x141>(z);
    z = dpp_add<0x140>(z);
    z += __shfl_xor(z, 16, 64);
    z += __shfl_xor(z, 32, 64);
    __syncthreads();
    if ((tid & 63) == 0) red[tid >> 6] = z;
    __syncthreads();
    if (tid == 0) {
        float s = ((red[0] + red[1]) + (red[2] + red[3])) + ((red[4] + red[5]) + (red[6] + red[7]));
        atomicAdd(&accs[2], s);
    }
}

// ---------------------------------------------------------------------------
// Kernel 2: decoder GEMM, f32 in/out, bf16 MFMA inside.
// ---------------------------------------------------------------------------
__global__ __launch_bounds__(256, 2) void dec_gemm(
    const float* __restrict__ pn_, const float* __restrict__ pm_,
    const float* __restrict__ wo, const float* __restrict__ bo,
    const float* __restrict__ wsd, const float* __restrict__ bsd,
    float* __restrict__ outO, float* __restrict__ outS)
{
    __shared__ u16 As[128 * 136];
    __shared__ u16 Bs[128 * 136];
    __shared__ float rnorm[128];
    int cb = blockIdx.x;
    int rowbase = blockIdx.y * 128;
    const float* W; const float* bias; float* out; int Nw; int colbase;
    if (cb < 4) { W = wo; bias = bo; out = outO; Nw = 512; colbase = cb * 128; }
    else        { W = wsd; bias = bsd; out = outS; Nw = 1024; colbase = (cb - 4) * 128; }
    int tid = threadIdx.x;
    for (int i = tid; i < 2048; i += 256) {
        int row = i >> 4, kb = i & 15;
        size_t go = ((size_t)(rowbase + row)) * 128 + kb * 8;
        f32x4 a0 = *(const f32x4*)(pn_ + go);
        f32x4 a1 = *(const f32x4*)(pn_ + go + 4);
        f32x4 m0v = *(const f32x4*)(pm_ + go);
        f32x4 m1v = *(const f32x4*)(pm_ + go + 4);
        f32x4 v0 = a0 + m0v, v1 = a1 + m1v;
        uint4 vv;
        vv.x = pack2(v0.x, v0.y); vv.y = pack2(v0.z, v0.w);
        vv.z = pack2(v1.x, v1.y); vv.w = pack2(v1.z, v1.w);
        *(uint4*)(As + row * 136 + kb * 8) = vv;
        size_t gw = ((size_t)(colbase + row)) * 128 + kb * 8;
        f32x4 w0 = *(const f32x4*)(W + gw);
        f32x4 w1 = *(const f32x4*)(W + gw + 4);
        uint4 wv;
        wv.x = pack2(w0.x, w0.y); wv.y = pack2(w0.z, w0.w);
        wv.z = pack2(w1.x, w1.y); wv.w = pack2(w1.z, w1.w);
        *(uint4*)(Bs + row * 136 + kb * 8) = wv;
    }
    __syncthreads();
    {
        int rr = tid >> 1, hh = tid & 1;
        const u16* rowp = As + rr * 136 + hh * 64;
        float ss = 0.f;
#pragma unroll
        for (int i = 0; i < 64; ++i) { float x = bf2f(rowp[i]); ss += x * x; }
        ss += __shfl_xor(ss, 1, 64);
        if (hh == 0) rnorm[rr] = 1.f / fmaxf(sqrtf(ss), 1e-12f);
    }
    __syncthreads();
    int wv_ = tid >> 6, lane = tid & 63;
    int m0 = (wv_ & 1) * 64, n0 = (wv_ >> 1) * 64;
    int lr = lane & 15, lq = lane >> 4;
    const f32x4 vzero = {0.f, 0.f, 0.f, 0.f};
    f32x4 acc[4][4];
#pragma unroll
    for (int a = 0; a < 4; ++a)
#pragma unroll
        for (int c = 0; c < 4; ++c) acc[a][c] = vzero;
#pragma unroll
    for (int ks = 0; ks < 4; ++ks) {
        bf16x8 af[4], bfr[4];
#pragma unroll
        for (int i = 0; i < 4; ++i) {
            af[i]  = *(const bf16x8*)(As + (m0 + i * 16 + lr) * 136 + ks * 32 + lq * 8);
            bfr[i] = *(const bf16x8*)(Bs + (n0 + i * 16 + lr) * 136 + ks * 32 + lq * 8);
        }
#pragma unroll
        for (int mi = 0; mi < 4; ++mi)
#pragma unroll
            for (int ni = 0; ni < 4; ++ni)
                acc[mi][ni] = __builtin_amdgcn_mfma_f32_16x16x32_bf16(af[mi], bfr[ni], acc[mi][ni], 0, 0, 0);
    }
#pragma unroll
    for (int ni = 0; ni < 4; ++ni) {
        int col = colbase + n0 + ni * 16 + lr;
        float bb = bias[col];
#pragma unroll
        for (int mi = 0; mi < 4; ++mi) {
            int rloc = m0 + mi * 16 + lq * 4;
            int row = rowbase + rloc;
#pragma unroll
            for (int k2 = 0; k2 < 4; ++k2) {
                out[((size_t)(row + k2)) * Nw + col] = acc[mi][ni][k2] * rnorm[rloc + k2] + bb;
            }
        }
    }
}

// ---------------------------------------------------------------------------
// Kernel 3: per-row logsumexp CE losses, f32 logits. One wave per row.
// ---------------------------------------------------------------------------
__global__ __launch_bounds__(256) void loss_rows(
    const float* __restrict__ lo_, const float* __restrict__ ls_,
    const int* __restrict__ obs, const int* __restrict__ states,
    float* __restrict__ accs)
{
    __shared__ float part[8];
    int wv = threadIdx.x >> 6, lane = threadIdx.x & 63;
    float accO = 0.f, accS = 0.f;
    int rowbase = blockIdx.x * 128 + wv * 32;
    for (int i = 0; i < 32; ++i) {
        int row = rowbase + i;
        {
            const float* ro = lo_ + ((size_t)row << 9);
            f32x4 u0 = *(const f32x4*)(ro + lane * 8);
            f32x4 u1 = *(const f32x4*)(ro + lane * 8 + 4);
            float m = fmaxf(fmaxf(fmaxf(u0.x, u0.y), fmaxf(u0.z, u0.w)),
                            fmaxf(fmaxf(u1.x, u1.y), fmaxf(u1.z, u1.w)));
#pragma unroll
            for (int k = 1; k < 64; k <<= 1) m = fmaxf(m, __shfl_xor(m, k, 64));
            float se = __expf(u0.x - m) + __expf(u0.y - m) + __expf(u0.z - m) + __expf(u0.w - m) +
                       __expf(u1.x - m) + __expf(u1.y - m) + __expf(u1.z - m) + __expf(u1.w - m);
#pragma unroll
            for (int k = 1; k < 64; k <<= 1) se += __shfl_xor(se, k, 64);
            float lse = m + __logf(se);
            float xt = ro[obs[row]];
            if (lane == 0) accO += lse - xt;
        }
        {
            const float* rs = ls_ + ((size_t)row << 10);
            f32x4 u0 = *(const f32x4*)(rs + lane * 16);
            f32x4 u1 = *(const f32x4*)(rs + lane * 16 + 4);
            f32x4 u2 = *(const f32x4*)(rs + lane * 16 + 8);
            f32x4 u3 = *(const f32x4*)(rs + lane * 16 + 12);
            float m = fmaxf(fmaxf(fmaxf(u0.x, u0.y), fmaxf(u0.z, u0.w)),
                            fmaxf(fmaxf(u1.x, u1.y), fmaxf(u1.z, u1.w)));
            m = fmaxf(m, fmaxf(fmaxf(fmaxf(u2.x, u2.y), fmaxf(u2.z, u2.w)),
                               fmaxf(fmaxf(u3.x, u3.y), fmaxf(u3.z, u3.w))));
#pragma unroll
            for (int k = 1; k < 64; k <<= 1) m = fmaxf(m, __shfl_xor(m, k, 64));
            float se = __expf(u0.x - m) + __expf(u0.y - m) + __expf(u0.z - m) + __expf(u0.w - m) +
                       __expf(u1.x - m) + __expf(u1.y - m) + __expf(u1.z - m) + __expf(u1.w - m) +
                       __expf(u2.x - m) + __expf(u2.y - m) + __expf(u2.z - m) + __expf(u2.w - m) +
                       __expf(u3.x - m) + __expf(u3.y - m) + __expf(u3.z - m) + __expf(u3.w - m);
#pragma unroll
            for (int k = 1; k < 64; k <<= 1) se += __shfl_xor(se, k, 64);
            float lse = m + __logf(se);
            float xt = rs[states[row]];
            if (lane == 0) accS += lse - xt;
        }
    }
    if (lane == 0) { part[wv] = accO; part[4 + wv] = accS; }
    __syncthreads();
    if (threadIdx.x == 0) {
        atomicAdd(&accs[0], part[0] + part[1] + part[2] + part[3]);
        atomicAdd(&accs[1], part[4] + part[5] + part[6] + part[7]);
    }
}

__global__ void finalize_kernel(const float* __restrict__ accs, float* __restrict__ out_loss)
{
    float lo = accs[0] * (1.f / 65536.f);
    float ls = accs[1] * (1.f / 65536.f);
    float lm = accs[2] * (1.f / (256.f * 255.f * 128.f));
    out_loss[0] = lo + 0.1f * lm + ls;
}

extern "C" void kernel_launch(void* const* d_in, const int* in_sizes, int n_in,
                              void* d_out, int out_size, void* d_ws, size_t ws_size,
                              hipStream_t stream)
{
    const int* obs        = (const int*)d_in[0];
    const int* actions    = (const int*)d_in[1];
    const int* states     = (const int*)d_in[2];
    const float* obs_emb  = (const float*)d_in[3];
    const float* act_emb  = (const float*)d_in[4];
    const float* g_init   = (const float*)d_in[5];
    const float* w_ih     = (const float*)d_in[6];
    const float* w_hh     = (const float*)d_in[7];
    const float* b_ih     = (const float*)d_in[8];
    const float* b_hh     = (const float*)d_in[9];
    const float* enc_w1   = (const float*)d_in[10];
    const float* enc_b1   = (const float*)d_in[11];
    const float* ln_g     = (const float*)d_in[12];
    const float* ln_b     = (const float*)d_in[13];
    const float* enc_w2   = (const float*)d_in[14];
    const float* enc_b2   = (const float*)d_in[15];
    const float* dec_obs_w = (const float*)d_in[16];
    const float* dec_obs_b = (const float*)d_in[17];
    const float* dec_st_w  = (const float*)d_in[18];
    const float* dec_st_b  = (const float*)d_in[19];

    float* out = (float*)d_out;
    float* outO    = out;                            // (B,T,512)
    float* outS    = out + (size_t)33554432;         // (B,T,1024)
    float* outP    = out + (size_t)100663296;        // (B,T,128) p_norm
    float* outPM   = out + (size_t)109051904;        // (B,T,128) p_mem
    float* outLoss = out + (size_t)117440512;        // scalar

    // scratch tables live at the start of the outS region: consumed by
    // scan_kernel, later fully overwritten by dec_gemm. Zero ws risk.
    float* hx_tab = outS;                 // 512*128 floats
    float* gi_tab = outS + 65536;         // 8*192 floats

    float* accs = (float*)d_ws;  // [0]=obs CE sum [1]=state CE sum [2]=mem MSE sum

    hipMemsetAsync(d_ws, 0, 64, stream);
    precompute_tabs<<<dim3(262), dim3(256), 0, stream>>>(
        obs_emb, act_emb, w_ih, b_ih, enc_w1, enc_b1, hx_tab, gi_tab);
    scan_kernel<<<dim3(256), dim3(512), 0, stream>>>(
        obs, actions, g_init, w_hh, b_hh,
        enc_w1, ln_g, ln_b, enc_w2, enc_b2, hx_tab, gi_tab, outP, outPM, accs);
    dec_gemm<<<dim3(12, 512), dim3(256), 0, stream>>>(
        outP, outPM, dec_obs_w, dec_obs_b, dec_st_w, dec_st_b, outO, outS);
    loss_rows<<<dim3(512), dim3(256), 0, stream>>>(outO, outS, obs, states, accs);
    finalize_kernel<<<dim3(1), dim3(1), 0, stream>>>(accs, outLoss);
}